// Round 10
// baseline (357.982 us; speedup 1.0000x reference)
//
#include <hip/hip_runtime.h>

typedef unsigned int uint;
typedef unsigned short ushort_t;
typedef short s8v __attribute__((ext_vector_type(8)));
typedef float f4v __attribute__((ext_vector_type(4)));

#define N_NODES 100000
#define N_EDGES 1600000
#define FEAT 32
#define HID 64
#define NCLS 10

#define BUCKET_SHIFT 8
#define NBUCKET 391              // ceil(100000 / 256)
#define NCB 256                  // blocks for bucket hist/scatter passes
#define CHUNK ((N_EDGES + NCB - 1) / NCB)   // 6250
#define BH_N (NBUCKET * NCB)     // 100096
#define NB_BH ((BH_N + 255) / 256)          // 391
#define CAP 6144                 // LDS staging capacity per bucket
#define LROW 65                  // padded LDS row stride (f32 words)

#define GRID_G 2048              // resident grid for gatherH (8 blocks/CU)
#define NPAIR (N_NODES / 2)      // 50000
#define SRCW (N_NODES * 8)       // 800000 words per half-array (3.2 MB)
#define WCHUNK ((SRCW + 255) / 256)  // 3125 words per warming chunk

// ---------------- bf16 pack/unpack helpers ----------------

__device__ __forceinline__ uint pack_bf16(float lo, float hi) {
    uint a = __float_as_uint(lo);
    uint b = __float_as_uint(hi);
    a = a + 0x7fffu + ((a >> 16) & 1u);
    b = b + 0x7fffu + ((b >> 16) & 1u);
    return (a >> 16) | (b & 0xffff0000u);
}
__device__ __forceinline__ float unp_lo(uint v) { return __uint_as_float(v << 16); }
__device__ __forceinline__ float unp_hi(uint v) { return __uint_as_float(v & 0xffff0000u); }

__device__ __forceinline__ s8v to_s8(uint4 u) {
    union { uint4 u; s8v s; } x;
    x.u = u;
    return x.s;
}

// ---------------- two-level counting sort: CSR build ----------------

__global__ void bucket_hist(const int* __restrict__ col, int* __restrict__ blockhist) {
    __shared__ int lh[NBUCKET];
    int blk = blockIdx.x;
    for (int i = threadIdx.x; i < NBUCKET; i += 256) lh[i] = 0;
    __syncthreads();
    int e0 = blk * CHUNK;
    int e1 = min(e0 + CHUNK, N_EDGES);
    for (int e = e0 + threadIdx.x; e < e1; e += 256)
        atomicAdd(&lh[col[e] >> BUCKET_SHIFT], 1);
    __syncthreads();
    for (int i = threadIdx.x; i < NBUCKET; i += 256)
        blockhist[i * NCB + blk] = lh[i];
}

__global__ void scanA_kernel(const int* __restrict__ src, int* __restrict__ dst,
                             int* __restrict__ bsum, int n) {
    __shared__ int s[256];
    int gid = blockIdx.x * 256 + threadIdx.x;
    int v = (gid < n) ? src[gid] : 0;
    s[threadIdx.x] = v;
    __syncthreads();
    for (int off = 1; off < 256; off <<= 1) {
        int t = (threadIdx.x >= off) ? s[threadIdx.x - off] : 0;
        __syncthreads();
        s[threadIdx.x] += t;
        __syncthreads();
    }
    if (gid < n) dst[gid] = s[threadIdx.x] - v;
    if (threadIdx.x == 255) bsum[blockIdx.x] = s[255];
}

__global__ void scanB_kernel(int* __restrict__ bsum, int nb) {
    __shared__ int s[512];
    int v = (threadIdx.x < nb) ? bsum[threadIdx.x] : 0;
    s[threadIdx.x] = v;
    __syncthreads();
    for (int off = 1; off < 512; off <<= 1) {
        int t = (threadIdx.x >= off) ? s[threadIdx.x - off] : 0;
        __syncthreads();
        s[threadIdx.x] += t;
        __syncthreads();
    }
    if (threadIdx.x < nb) bsum[threadIdx.x] = s[threadIdx.x] - v;
}

__global__ void scanC_add(int* __restrict__ dst, const int* __restrict__ bsum, int n) {
    int gid = blockIdx.x * 256 + threadIdx.x;
    if (gid < n) dst[gid] += bsum[blockIdx.x];
}

__global__ void bucket_scatter(const int* __restrict__ row, const int* __restrict__ col,
                               const int* __restrict__ base, int* __restrict__ packed) {
    __shared__ int lcnt[NBUCKET];
    __shared__ int lbase[NBUCKET];
    int blk = blockIdx.x;
    for (int i = threadIdx.x; i < NBUCKET; i += 256) {
        lcnt[i] = 0;
        lbase[i] = base[i * NCB + blk];
    }
    __syncthreads();
    int e0 = blk * CHUNK;
    int e1 = min(e0 + CHUNK, N_EDGES);
    for (int e = e0 + threadIdx.x; e < e1; e += 256) {
        int c = col[e];
        int r = row[e];
        int b = c >> BUCKET_SHIFT;
        int pos = lbase[b] + atomicAdd(&lcnt[b], 1);
        packed[pos] = (r << BUCKET_SHIFT) | (c & 255);
    }
}

// one block per bucket: 512-key (dst_local, src>=65536) sort; writes rowptr, nmid, dinv, elo
__global__ void bucket_sort(const int* __restrict__ base, const int* __restrict__ packed,
                            int* __restrict__ rowptr, ushort_t* __restrict__ elo,
                            ushort_t* __restrict__ nmid, float* __restrict__ dinv) {
    __shared__ int stage[CAP];
    __shared__ int cnt[512];
    __shared__ int excl[512];
    __shared__ int psum[256];
    int b = blockIdx.x;
    int tid = threadIdx.x;
    int s = base[b * NCB];
    int e = (b == NBUCKET - 1) ? N_EDGES : base[(b + 1) * NCB];
    int m = e - s;
    cnt[tid] = 0;
    cnt[tid + 256] = 0;
    __syncthreads();
    for (int i = tid; i < m; i += 256) {
        int p = packed[s + i];
        if (i < CAP) stage[i] = p;
        int r = p >> BUCKET_SHIFT;
        int key = ((p & 255) << 1) | (r >= 65536);
        atomicAdd(&cnt[key], 1);
    }
    __syncthreads();
    int c0 = cnt[2 * tid], c1 = cnt[2 * tid + 1];
    psum[tid] = c0 + c1;
    __syncthreads();
    for (int off = 1; off < 256; off <<= 1) {
        int t = (tid >= off) ? psum[tid - off] : 0;
        __syncthreads();
        psum[tid] += t;
        __syncthreads();
    }
    int tot = c0 + c1;
    int pex = psum[tid] - tot;
    excl[2 * tid] = pex;
    excl[2 * tid + 1] = pex + c0;
    int node = (b << BUCKET_SHIFT) + tid;
    if (node < N_NODES) {
        dinv[node] = (tot > 0) ? rsqrtf((float)tot) : 0.0f;
        rowptr[node] = s + pex;
        nmid[node] = (ushort_t)c0;
    }
    if (b == NBUCKET - 1 && tid == 0) rowptr[N_NODES] = N_EDGES;
    __syncthreads();
    cnt[tid] = 0;
    cnt[tid + 256] = 0;
    __syncthreads();
    for (int i = tid; i < m; i += 256) {
        int p = (i < CAP) ? stage[i] : packed[s + i];
        int r = p >> BUCKET_SHIFT;
        int key = ((p & 255) << 1) | (r >= 65536);
        int pos = excl[key] + atomicAdd(&cnt[key], 1);
        elo[s + pos] = (ushort_t)r;
    }
}

// ---------------- prescale: t0 halves = bf16(dinv * x) ----------------

__global__ void prescale_kernel(const float* __restrict__ x, const float* __restrict__ dinv,
                                uint* __restrict__ t0) {
    int i = blockIdx.x * 256 + threadIdx.x;
    if (i < N_NODES * 16) {
        int node = i >> 4, fpf = i & 15;
        float dv = dinv[node];
        uint pv = pack_bf16(x[node * 32 + 2 * fpf] * dv, x[node * 32 + 2 * fpf + 1] * dv);
        t0[(size_t)(fpf >> 3) * SRCW + node * 8 + (fpf & 7)] = pv;
    }
}

// ---------------- unified half-width gather with L2-warming prologue ----------------
// 32 B bf16 rows (8 packed pairs). 2 nodes/wave, grid-stride, resident grid.
// MODE 0: layer1 hop (out0 = dinv*sum, out1 = dinv^2*sum)
// MODE 1: layer1 last hop (out0 only)
// MODE 2: horner mid (v = add + dinv*sum; out0 = dinv*v)
// MODE 3: horner final (v = add + dinv*sum; outF = f32 log_softmax(v))
template <int MODE>
__global__ __launch_bounds__(256) void gatherH_kernel(
        const int* __restrict__ rowptr, const ushort_t* __restrict__ elo,
        const ushort_t* __restrict__ nmid, const float* __restrict__ dinv,
        const uint* __restrict__ src, const uint* __restrict__ add,
        uint* __restrict__ out0, uint* __restrict__ out1, float* __restrict__ outF) {
    // ---- warming: blockIdx%8 ~ XCD round-robin; each XCD streams the full src ----
    {
        int cid = blockIdx.x >> 3;  // 0..255
        int a0 = cid * WCHUNK;
        int a1 = min(a0 + WCHUNK, SRCW);
        uint d = 0;
        for (int i = a0 + threadIdx.x; i < a1; i += 256) d += src[i];
        asm volatile("" :: "v"(d));
    }

    int lane = threadIdx.x & 63;
    int half = lane >> 5;     // which node of the pair
    int fp = lane & 7;        // feature pair 0..7
    int g = (lane >> 3) & 3;  // 4 edge groups
    int wid = (blockIdx.x * 256 + threadIdx.x) >> 6;
    const int NW = GRID_G * 4;

    for (int p = wid; p < NPAIR; p += NW) {
        int node = p * 2 + half;
        int s = rowptr[node], e = rowptr[node + 1];
        int smid = s + nmid[node];
        float acc0 = 0.0f, acc1 = 0.0f;
        int base = (s & ~3) + g * 4;
        for (int b = base; b < e; b += 16) {
            const uint* ep = (const uint*)(elo + b);
            uint e0 = __builtin_nontemporal_load(ep);
            uint e1 = __builtin_nontemporal_load(ep + 1);
            int i0 = (int)(e0 & 0xffffu) | ((b     >= smid) ? 0x10000 : 0);
            int i1 = (int)(e0 >> 16)     | ((b + 1 >= smid) ? 0x10000 : 0);
            int i2 = (int)(e1 & 0xffffu) | ((b + 2 >= smid) ? 0x10000 : 0);
            int i3 = (int)(e1 >> 16)     | ((b + 3 >= smid) ? 0x10000 : 0);
            uint v0 = (b     >= s && b     < e) ? src[i0 * 8 + fp] : 0u;
            uint v1 = (b + 1 >= s && b + 1 < e) ? src[i1 * 8 + fp] : 0u;
            uint v2 = (b + 2 >= s && b + 2 < e) ? src[i2 * 8 + fp] : 0u;
            uint v3 = (b + 3 >= s && b + 3 < e) ? src[i3 * 8 + fp] : 0u;
            acc0 += unp_lo(v0) + unp_lo(v1) + unp_lo(v2) + unp_lo(v3);
            acc1 += unp_hi(v0) + unp_hi(v1) + unp_hi(v2) + unp_hi(v3);
        }
        acc0 += __shfl_xor(acc0, 8);
        acc0 += __shfl_xor(acc0, 16);
        acc1 += __shfl_xor(acc1, 8);
        acc1 += __shfl_xor(acc1, 16);
        float dv = dinv[node];
        if (MODE <= 1) {
            if (g == 0) {
                uint pv = pack_bf16(dv * acc0, dv * acc1);
                __builtin_nontemporal_store(pv, out0 + node * 8 + fp);
                if (MODE == 0) {
                    float d2 = dv * dv;
                    uint qv = pack_bf16(d2 * acc0, d2 * acc1);
                    __builtin_nontemporal_store(qv, out1 + node * 8 + fp);
                }
            }
        } else {
            uint av = __builtin_nontemporal_load(add + node * 8 + fp);
            float v0 = unp_lo(av) + dv * acc0;
            float v1 = unp_hi(av) + dv * acc1;
            if (MODE == 2) {
                if (g == 0) {
                    uint pv = pack_bf16(dv * v0, dv * v1);
                    __builtin_nontemporal_store(pv, out0 + node * 8 + fp);
                }
            } else {
                float l0 = (2 * fp     < NCLS) ? v0 : -1e30f;
                float l1 = (2 * fp + 1 < NCLS) ? v1 : -1e30f;
                float m = fmaxf(l0, l1);
                m = fmaxf(m, __shfl_xor(m, 1));
                m = fmaxf(m, __shfl_xor(m, 2));
                m = fmaxf(m, __shfl_xor(m, 4));
                float ex = ((2 * fp     < NCLS) ? __expf(l0 - m) : 0.0f)
                         + ((2 * fp + 1 < NCLS) ? __expf(l1 - m) : 0.0f);
                ex += __shfl_xor(ex, 1);
                ex += __shfl_xor(ex, 2);
                ex += __shfl_xor(ex, 4);
                float ls = logf(ex) + m;
                if (g == 0 && fp < 5) {
                    float2 o = {l0 - ls, l1 - ls};
                    *(float2*)(outF + (size_t)node * 10 + 2 * fp) = o;
                }
            }
        }
    }
}

// ---------------- weight pre-pack into B-fragment order (bf16) ----------------

__global__ void wfprep_kernel(const float* __restrict__ W1, const float* __restrict__ W2,
                              uint* __restrict__ wf1, uint* __restrict__ wf2) {
    int idx = blockIdx.x * 256 + threadIdx.x;
    if (idx < 4096) {
        int vj = idx & 3, frag = idx >> 2;
        int lane = frag & 63, ks = (frag >> 6) & 3, nt = frag >> 8;
        int g = lane >> 4, c = lane & 15;
        int k0 = ks * 32 + g * 8 + 2 * vj;
        int n = nt * 16 + c;
        wf1[idx] = pack_bf16(W1[k0 * 64 + n], W1[(k0 + 1) * 64 + n]);
    } else if (idx < 6144) {
        int i2 = idx - 4096;
        int vj = i2 & 3, frag = i2 >> 2;
        int lane = frag & 63, ks = (frag >> 6) & 1, nt = frag >> 7;
        int g = lane >> 4, c = lane & 15;
        int k0 = ks * 32 + g * 8 + 2 * vj;
        float v0 = (c < NCLS) ? W2[(nt * HID + k0) * NCLS + c] : 0.0f;
        float v1 = (c < NCLS) ? W2[(nt * HID + k0 + 1) * NCLS + c] : 0.0f;
        wf2[i2] = pack_bf16(v0, v1);
    }
}

// ---------------- fused dense: h = relu([x|p1|p2|p3]@W1+b1); z = bf16(h@W2stack) 32B rows ----------------

__global__ __launch_bounds__(256) void dense_fused(
        const float* __restrict__ x, const uint* __restrict__ p1,
        const uint* __restrict__ p2, const uint* __restrict__ p3,
        const uint* __restrict__ wf1, const uint* __restrict__ wf2,
        const float* __restrict__ b1, const float* __restrict__ b2,
        const float* __restrict__ dinv, uint* __restrict__ z) {
    __shared__ float hls[4 * 16 * LROW];
    int tid = threadIdx.x;
    int wv = tid >> 6, l = tid & 63, g = l >> 4, c = l & 15;
    float* my = hls + wv * 16 * LROW;
    int row0 = blockIdx.x * 64 + wv * 16;
    int ra = row0 + c;
    int rc = min(ra, N_NODES - 1);

    // ---- stage 1: A-frags straight from global (p arrays in halves at stride SRCW) ----
    size_t hofs = (size_t)(g >> 1) * SRCW + rc * 8 + (g & 1) * 4;
    uint4 au0;
    {
        float4 xa = *(const float4*)(x + rc * 32 + g * 8);
        float4 xb = *(const float4*)(x + rc * 32 + g * 8 + 4);
        au0.x = pack_bf16(xa.x, xa.y);
        au0.y = pack_bf16(xa.z, xa.w);
        au0.z = pack_bf16(xb.x, xb.y);
        au0.w = pack_bf16(xb.z, xb.w);
    }
    uint4 au1 = *(const uint4*)(p1 + hofs);
    uint4 au2 = *(const uint4*)(p2 + hofs);
    uint4 au3 = *(const uint4*)(p3 + hofs);
    s8v a0 = to_s8(au0), a1 = to_s8(au1), a2 = to_s8(au2), a3 = to_s8(au3);

    f4v acc[4];
#pragma unroll
    for (int nt = 0; nt < 4; nt++) {
        f4v ac = {0.f, 0.f, 0.f, 0.f};
        const s8v* wp = (const s8v*)(wf1 + (nt * 4) * 64 * 4 + l * 4);
        ac = __builtin_amdgcn_mfma_f32_16x16x32_bf16(a0, wp[0 * 64], ac, 0, 0, 0);
        ac = __builtin_amdgcn_mfma_f32_16x16x32_bf16(a1, wp[1 * 64], ac, 0, 0, 0);
        ac = __builtin_amdgcn_mfma_f32_16x16x32_bf16(a2, wp[2 * 64], ac, 0, 0, 0);
        ac = __builtin_amdgcn_mfma_f32_16x16x32_bf16(a3, wp[3 * 64], ac, 0, 0, 0);
        acc[nt] = ac;
    }

    // ---- epilogue 1: bias + relu -> padded LDS tile ----
#pragma unroll
    for (int nt = 0; nt < 4; nt++) {
        float bb = b1[nt * 16 + c];
#pragma unroll
        for (int reg = 0; reg < 4; reg++) {
            my[(4 * g + reg) * LROW + nt * 16 + c] = fmaxf(acc[nt][reg] + bb, 0.0f);
        }
    }
    __syncthreads();

    // ---- stage 2: re-fragment from LDS, second MFMA ----
    uint4 b2u[2];
#pragma unroll
    for (int ks = 0; ks < 2; ks++) {
        float4 h0 = *(const float4*)&my[c * LROW + ks * 32 + g * 8];
        float4 h1 = *(const float4*)&my[c * LROW + ks * 32 + g * 8 + 4];
        b2u[ks].x = pack_bf16(h0.x, h0.y);
        b2u[ks].y = pack_bf16(h0.z, h0.w);
        b2u[ks].z = pack_bf16(h1.x, h1.y);
        b2u[ks].w = pack_bf16(h1.z, h1.w);
    }
    s8v h0f = to_s8(b2u[0]), h1f = to_s8(b2u[1]);

    f4v acc2[4];
#pragma unroll
    for (int nt = 0; nt < 4; nt++) {
        f4v ac = {0.f, 0.f, 0.f, 0.f};
        const s8v* wp = (const s8v*)(wf2 + (nt * 2) * 64 * 4 + l * 4);
        ac = __builtin_amdgcn_mfma_f32_16x16x32_bf16(h0f, wp[0 * 64], ac, 0, 0, 0);
        ac = __builtin_amdgcn_mfma_f32_16x16x32_bf16(h1f, wp[1 * 64], ac, 0, 0, 0);
        acc2[nt] = ac;
    }

    // ---- epilogue 2: bias (k=0), dinv prescale (k=3), pack pairs via shfl, store bf16 z ----
#pragma unroll
    for (int nt = 0; nt < 4; nt++) {
        float bb = (nt == 0 && c < NCLS) ? b2[c] : 0.0f;
        uint* zk = z + (size_t)nt * SRCW;
#pragma unroll
        for (int reg = 0; reg < 4; reg++) {
            int rr = row0 + 4 * g + reg;
            float v = acc2[nt][reg] + bb;
            if (nt == 3) v *= dinv[min(rr, N_NODES - 1)];
            float vn = __shfl_xor(v, 1);  // col c^1's value
            if (rr < N_NODES && (c & 1) == 0) {
                zk[rr * 8 + (c >> 1)] = pack_bf16(v, vn);
            }
        }
    }
}

// ---------------- launcher ----------------

extern "C" void kernel_launch(void* const* d_in, const int* in_sizes, int n_in,
                              void* d_out, int out_size, void* d_ws, size_t ws_size,
                              hipStream_t stream) {
    const float* x  = (const float*)d_in[0];
    const int*   ei = (const int*)d_in[1];
    const float* W1 = (const float*)d_in[2];
    const float* b1 = (const float*)d_in[3];
    const float* W2 = (const float*)d_in[4];
    const float* b2 = (const float*)d_in[5];
    float* out = (float*)d_out;

    const int* row = ei;
    const int* col = ei + N_EDGES;

    float* w = (float*)d_ws;
    size_t o = 0;
    auto alloc = [&](size_t nel) { float* p = w + o; o += (nel + 63) & ~(size_t)63; return p; };

    int*      rowptr = (int*)alloc(N_NODES + 1);
    int*      bsum   = (int*)alloc(512);
    float*    dinv   = alloc(N_NODES);
    ushort_t* nmid   = (ushort_t*)alloc(50048);          // 100096 ushorts
    uint*     wf1    = (uint*)alloc(4096);
    uint*     wf2    = (uint*)alloc(2048);
    ushort_t* elo    = (ushort_t*)alloc(800064);         // 1.6M+ ushorts (+pad)
    float*    bufA   = alloc((size_t)N_NODES * 32);
    float*    bufB   = alloc((size_t)N_NODES * 32);
    float*    bufC   = alloc((size_t)N_NODES * 32);
    float*    bufD   = alloc((size_t)N_NODES * 32);
    float*    h      = alloc((size_t)N_NODES * HID);     // holds z0..z3 after dense

    // CSR-build temporaries alias later buffers (build completes first)
    int* blockhist = (int*)bufB;
    int* bhbase    = (int*)bufC;
    int* packed    = (int*)h;

    // half-feature bf16 buffers: each logical 32-wide array = 2 halves at stride SRCW
    uint* t0  = (uint*)bufA;
    uint* p1  = (uint*)bufB;
    uint* p1p = (uint*)bufC;
    uint* p2  = (uint*)bufD;
    uint* p2p = (uint*)bufA;   // t0 dead after hop1
    uint* p3  = (uint*)bufC;   // p1p dead after hop2
    // layer-2 z buffers (each N*8 uints = 3.2 MB), z_k at k*SRCW in h region
    uint* z  = (uint*)h;
    uint* tA = (uint*)bufD;    // p2 dead after dense
    uint* tB = (uint*)bufA;    // p2p dead after hop3

    const int TB = 256;

    // --- CSR build ---
    bucket_hist<<<NCB, TB, 0, stream>>>(col, blockhist);
    scanA_kernel<<<NB_BH, TB, 0, stream>>>(blockhist, bhbase, bsum, BH_N);
    scanB_kernel<<<1, 512, 0, stream>>>(bsum, NB_BH);
    scanC_add<<<NB_BH, TB, 0, stream>>>(bhbase, bsum, BH_N);
    bucket_scatter<<<NCB, TB, 0, stream>>>(row, col, bhbase, packed);
    bucket_sort<<<NBUCKET, TB, 0, stream>>>(bhbase, packed, rowptr, elo, nmid, dinv);

    // --- weight pre-pack (tiny) ---
    wfprep_kernel<<<24, TB, 0, stream>>>(W1, W2, wf1, wf2);

    // --- layer 1 (bf16 propagation, half-feature passes with L2 warming) ---
    prescale_kernel<<<(N_NODES * 16 + TB - 1) / TB, TB, 0, stream>>>(x, dinv, t0);
    for (int hh = 0; hh < 2; hh++)
        gatherH_kernel<0><<<GRID_G, TB, 0, stream>>>(rowptr, elo, nmid, dinv,
            t0 + hh * (size_t)SRCW, nullptr, p1 + hh * (size_t)SRCW, p1p + hh * (size_t)SRCW, nullptr);
    for (int hh = 0; hh < 2; hh++)
        gatherH_kernel<0><<<GRID_G, TB, 0, stream>>>(rowptr, elo, nmid, dinv,
            p1p + hh * (size_t)SRCW, nullptr, p2 + hh * (size_t)SRCW, p2p + hh * (size_t)SRCW, nullptr);
    for (int hh = 0; hh < 2; hh++)
        gatherH_kernel<1><<<GRID_G, TB, 0, stream>>>(rowptr, elo, nmid, dinv,
            p2p + hh * (size_t)SRCW, nullptr, p3 + hh * (size_t)SRCW, nullptr, nullptr);

    // --- fused dense: both layers' GEMMs on the matrix pipe ---
    int gF = (N_NODES + 63) / 64;  // 1563
    dense_fused<<<gF, TB, 0, stream>>>(x, p1, p2, p3, wf1, wf2, b1, b2, dinv, z);

    // --- layer-2 Horner at width 16 (bf16, warmed) ---
    gatherH_kernel<2><<<GRID_G, TB, 0, stream>>>(rowptr, elo, nmid, dinv,
        z + 3 * (size_t)SRCW, z + 2 * (size_t)SRCW, tA, nullptr, nullptr);
    gatherH_kernel<2><<<GRID_G, TB, 0, stream>>>(rowptr, elo, nmid, dinv,
        tA, z + 1 * (size_t)SRCW, tB, nullptr, nullptr);
    gatherH_kernel<3><<<GRID_G, TB, 0, stream>>>(rowptr, elo, nmid, dinv,
        tB, z, nullptr, nullptr, out);
}

// Round 11
// 285.383 us; speedup vs baseline: 1.2544x; 1.2544x over previous
//
#include <hip/hip_runtime.h>

typedef unsigned int uint;
typedef short s8v __attribute__((ext_vector_type(8)));
typedef float f4v __attribute__((ext_vector_type(4)));

#define N_NODES 100000
#define N_EDGES 1600000
#define FEAT 32
#define HID 64
#define NCLS 10

#define BUCKET_SHIFT 8
#define NBUCKET 391              // ceil(100000 / 256)
#define NCB 256                  // blocks for bucket hist/scatter passes
#define CHUNK ((N_EDGES + NCB - 1) / NCB)   // 6250
#define BH_N (NBUCKET * NCB)     // 100096
#define NB_BH ((BH_N + 255) / 256)          // 391
#define CAP 6144                 // LDS staging capacity per bucket
#define LROW 65                  // padded LDS row stride (f32 words)

// ---------------- bf16 pack/unpack helpers ----------------

__device__ __forceinline__ uint pack_bf16(float lo, float hi) {
    uint a = __float_as_uint(lo);
    uint b = __float_as_uint(hi);
    a = a + 0x7fffu + ((a >> 16) & 1u);
    b = b + 0x7fffu + ((b >> 16) & 1u);
    return (a >> 16) | (b & 0xffff0000u);
}
__device__ __forceinline__ float unp_lo(uint v) { return __uint_as_float(v << 16); }
__device__ __forceinline__ float unp_hi(uint v) { return __uint_as_float(v & 0xffff0000u); }

__device__ __forceinline__ s8v to_s8(uint4 u) {
    union { uint4 u; s8v s; } x;
    x.u = u;
    return x.s;
}

// ---------------- two-level counting sort: CSR build ----------------

__global__ void bucket_hist(const int* __restrict__ col, int* __restrict__ blockhist) {
    __shared__ int lh[NBUCKET];
    int blk = blockIdx.x;
    for (int i = threadIdx.x; i < NBUCKET; i += 256) lh[i] = 0;
    __syncthreads();
    int e0 = blk * CHUNK;
    int e1 = min(e0 + CHUNK, N_EDGES);
    for (int e = e0 + threadIdx.x; e < e1; e += 256)
        atomicAdd(&lh[col[e] >> BUCKET_SHIFT], 1);
    __syncthreads();
    for (int i = threadIdx.x; i < NBUCKET; i += 256)
        blockhist[i * NCB + blk] = lh[i];
}

__global__ void scanA_kernel(const int* __restrict__ src, int* __restrict__ dst,
                             int* __restrict__ bsum, int n) {
    __shared__ int s[256];
    int gid = blockIdx.x * 256 + threadIdx.x;
    int v = (gid < n) ? src[gid] : 0;
    s[threadIdx.x] = v;
    __syncthreads();
    for (int off = 1; off < 256; off <<= 1) {
        int t = (threadIdx.x >= off) ? s[threadIdx.x - off] : 0;
        __syncthreads();
        s[threadIdx.x] += t;
        __syncthreads();
    }
    if (gid < n) dst[gid] = s[threadIdx.x] - v;
    if (threadIdx.x == 255) bsum[blockIdx.x] = s[255];
}

__global__ void scanB_kernel(int* __restrict__ bsum, int nb) {
    __shared__ int s[512];
    int v = (threadIdx.x < nb) ? bsum[threadIdx.x] : 0;
    s[threadIdx.x] = v;
    __syncthreads();
    for (int off = 1; off < 512; off <<= 1) {
        int t = (threadIdx.x >= off) ? s[threadIdx.x - off] : 0;
        __syncthreads();
        s[threadIdx.x] += t;
        __syncthreads();
    }
    if (threadIdx.x < nb) bsum[threadIdx.x] = s[threadIdx.x] - v;
}

__global__ void scanC_add(int* __restrict__ dst, const int* __restrict__ bsum, int n) {
    int gid = blockIdx.x * 256 + threadIdx.x;
    if (gid < n) dst[gid] += bsum[blockIdx.x];
}

__global__ void bucket_scatter(const int* __restrict__ row, const int* __restrict__ col,
                               const int* __restrict__ base, int* __restrict__ packed) {
    __shared__ int lcnt[NBUCKET];
    __shared__ int lbase[NBUCKET];
    int blk = blockIdx.x;
    for (int i = threadIdx.x; i < NBUCKET; i += 256) {
        lcnt[i] = 0;
        lbase[i] = base[i * NCB + blk];
    }
    __syncthreads();
    int e0 = blk * CHUNK;
    int e1 = min(e0 + CHUNK, N_EDGES);
    for (int e = e0 + threadIdx.x; e < e1; e += 256) {
        int c = col[e];
        int r = row[e];
        int b = c >> BUCKET_SHIFT;
        int pos = lbase[b] + atomicAdd(&lcnt[b], 1);
        packed[pos] = (r << BUCKET_SHIFT) | (c & 255);
    }
}

__global__ void bucket_sort(const int* __restrict__ base, const int* __restrict__ packed,
                            int* __restrict__ rowptr, int* __restrict__ eidx,
                            float* __restrict__ dinv) {
    __shared__ int stage[CAP];
    __shared__ int cnt[256];
    __shared__ int lscan[256];
    int b = blockIdx.x;
    int tid = threadIdx.x;
    int s = base[b * NCB];
    int e = (b == NBUCKET - 1) ? N_EDGES : base[(b + 1) * NCB];
    int m = e - s;
    bool fits = (m <= CAP);
    cnt[tid] = 0;
    __syncthreads();
    for (int i = tid; i < m; i += 256) {
        int p = packed[s + i];
        if (fits) stage[i] = p;
        atomicAdd(&cnt[p & 255], 1);
    }
    __syncthreads();
    int node = (b << BUCKET_SHIFT) + tid;
    int c = cnt[tid];
    if (node < N_NODES) dinv[node] = (c > 0) ? rsqrtf((float)c) : 0.0f;
    lscan[tid] = c;
    __syncthreads();
    for (int off = 1; off < 256; off <<= 1) {
        int t = (tid >= off) ? lscan[tid - off] : 0;
        __syncthreads();
        lscan[tid] += t;
        __syncthreads();
    }
    int excl = lscan[tid] - c;
    if (node < N_NODES) rowptr[node] = s + excl;
    if (b == NBUCKET - 1 && tid == 0) rowptr[N_NODES] = N_EDGES;
    __syncthreads();
    lscan[tid] = excl;
    cnt[tid] = 0;
    __syncthreads();
    for (int i = tid; i < m; i += 256) {
        int p = fits ? stage[i] : packed[s + i];
        int cl = p & 255;
        int pos = lscan[cl] + atomicAdd(&cnt[cl], 1);
        eidx[s + pos] = p >> BUCKET_SHIFT;
    }
}

// ---------------- prescale: t0 = bf16(dinv * x), packed pairs ----------------

__global__ void prescale_kernel(const float* __restrict__ x, const float* __restrict__ dinv,
                                uint* __restrict__ t0) {
    int i = blockIdx.x * 256 + threadIdx.x;
    if (i < N_NODES * 16) {
        int node = i >> 4, fp = i & 15;
        float dv = dinv[node];
        t0[i] = pack_bf16(x[node * 32 + 2 * fp] * dv, x[node * 32 + 2 * fp + 1] * dv);
    }
}

// ---------------- gather hops ----------------

// 32-wide bf16 (layer 1), 1 node/wave
template <int WP>
__global__ void gather32_kernel(const int* __restrict__ rowptr, const int* __restrict__ eidx,
                                const float* __restrict__ dinv, const uint* __restrict__ src,
                                uint* __restrict__ pout, uint* __restrict__ preout) {
    int node = (blockIdx.x * blockDim.x + threadIdx.x) >> 6;
    if (node >= N_NODES) return;
    int lane = threadIdx.x & 63;
    int fp = lane & 15;
    int g = lane >> 4;
    int s = rowptr[node], e = rowptr[node + 1];
    float acc0 = 0.0f, acc1 = 0.0f;
    int base = (s & ~3) + g * 4;
    for (int b = base; b < e; b += 16) {
        int4 q = *(const int4*)(eidx + b);
        uint v0 = (b     >= s && b     < e) ? src[q.x * 16 + fp] : 0u;
        uint v1 = (b + 1 >= s && b + 1 < e) ? src[q.y * 16 + fp] : 0u;
        uint v2 = (b + 2 >= s && b + 2 < e) ? src[q.z * 16 + fp] : 0u;
        uint v3 = (b + 3 >= s && b + 3 < e) ? src[q.w * 16 + fp] : 0u;
        acc0 += unp_lo(v0) + unp_lo(v1) + unp_lo(v2) + unp_lo(v3);
        acc1 += unp_hi(v0) + unp_hi(v1) + unp_hi(v2) + unp_hi(v3);
    }
    acc0 += __shfl_xor(acc0, 16);
    acc0 += __shfl_xor(acc0, 32);
    acc1 += __shfl_xor(acc1, 16);
    acc1 += __shfl_xor(acc1, 32);
    if (lane < 16) {
        float dv = dinv[node];
        pout[node * 16 + fp] = pack_bf16(dv * acc0, dv * acc1);
        if (WP) {
            float d2 = dv * dv;
            preout[node * 16 + fp] = pack_bf16(d2 * acc0, d2 * acc1);
        }
    }
}

// 16-wide bf16 Horner step, 2 nodes/wave.
//   v = add + dinv*sum;  FINAL=0: out=bf16(dinv*v)  FINAL=1: out=f32 log_softmax(v)
template <int FINAL>
__global__ void gather16_kernel(const int* __restrict__ rowptr, const int* __restrict__ eidx,
                                const float* __restrict__ dinv, const uint* __restrict__ src,
                                const uint* __restrict__ add, void* __restrict__ outv) {
    int wid = (blockIdx.x * blockDim.x + threadIdx.x) >> 6;
    int lane = threadIdx.x & 63;
    int node = wid * 2 + (lane >> 5);
    if (node >= N_NODES) return;
    int fp = lane & 7;        // feature pair 0..7
    int g = (lane >> 3) & 3;  // 4 edge groups
    int s = rowptr[node], e = rowptr[node + 1];
    float acc0 = 0.0f, acc1 = 0.0f;
    int base = (s & ~3) + g * 4;
    for (int b = base; b < e; b += 16) {
        int4 q = *(const int4*)(eidx + b);
        uint v0 = (b     >= s && b     < e) ? src[q.x * 8 + fp] : 0u;
        uint v1 = (b + 1 >= s && b + 1 < e) ? src[q.y * 8 + fp] : 0u;
        uint v2 = (b + 2 >= s && b + 2 < e) ? src[q.z * 8 + fp] : 0u;
        uint v3 = (b + 3 >= s && b + 3 < e) ? src[q.w * 8 + fp] : 0u;
        acc0 += unp_lo(v0) + unp_lo(v1) + unp_lo(v2) + unp_lo(v3);
        acc1 += unp_hi(v0) + unp_hi(v1) + unp_hi(v2) + unp_hi(v3);
    }
    // reduce over the 4 edge groups (lane bits 3,4)
    acc0 += __shfl_xor(acc0, 8);
    acc0 += __shfl_xor(acc0, 16);
    acc1 += __shfl_xor(acc1, 8);
    acc1 += __shfl_xor(acc1, 16);
    float dv = dinv[node];
    uint av = add[node * 8 + fp];
    float v0 = unp_lo(av) + dv * acc0;
    float v1 = unp_hi(av) + dv * acc1;
    if (!FINAL) {
        if (g == 0) ((uint*)outv)[node * 8 + fp] = pack_bf16(dv * v0, dv * v1);
    } else {
        float l0 = (2 * fp     < NCLS) ? v0 : -1e30f;
        float l1 = (2 * fp + 1 < NCLS) ? v1 : -1e30f;
        float m = fmaxf(l0, l1);
        m = fmaxf(m, __shfl_xor(m, 1));
        m = fmaxf(m, __shfl_xor(m, 2));
        m = fmaxf(m, __shfl_xor(m, 4));
        float ex = ((2 * fp     < NCLS) ? __expf(l0 - m) : 0.0f)
                 + ((2 * fp + 1 < NCLS) ? __expf(l1 - m) : 0.0f);
        ex += __shfl_xor(ex, 1);
        ex += __shfl_xor(ex, 2);
        ex += __shfl_xor(ex, 4);
        float ls = logf(ex) + m;
        if (g == 0 && fp < 5) {
            float2 o = {l0 - ls, l1 - ls};
            *(float2*)((float*)outv + (size_t)node * 10 + 2 * fp) = o;
        }
    }
}

// ---------------- weight pre-pack into B-fragment order (bf16) ----------------

__global__ void wfprep_kernel(const float* __restrict__ W1, const float* __restrict__ W2,
                              uint* __restrict__ wf1, uint* __restrict__ wf2) {
    int idx = blockIdx.x * 256 + threadIdx.x;
    if (idx < 4096) {
        int vj = idx & 3, frag = idx >> 2;
        int lane = frag & 63, ks = (frag >> 6) & 3, nt = frag >> 8;
        int g = lane >> 4, c = lane & 15;
        int k0 = ks * 32 + g * 8 + 2 * vj;
        int n = nt * 16 + c;
        wf1[idx] = pack_bf16(W1[k0 * 64 + n], W1[(k0 + 1) * 64 + n]);
    } else if (idx < 6144) {
        int i2 = idx - 4096;
        int vj = i2 & 3, frag = i2 >> 2;
        int lane = frag & 63, ks = (frag >> 6) & 1, nt = frag >> 7;
        int g = lane >> 4, c = lane & 15;
        int k0 = ks * 32 + g * 8 + 2 * vj;
        float v0 = (c < NCLS) ? W2[(nt * HID + k0) * NCLS + c] : 0.0f;
        float v1 = (c < NCLS) ? W2[(nt * HID + k0 + 1) * NCLS + c] : 0.0f;
        wf2[i2] = pack_bf16(v0, v1);
    }
}

// ---------------- fused dense: h = relu([x|p1|p2|p3]@W1+b1); z = bf16(h@W2stack (+b2, k3*dinv)) ----------------

__global__ __launch_bounds__(256) void dense_fused(
        const float* __restrict__ x, const uint* __restrict__ p1,
        const uint* __restrict__ p2, const uint* __restrict__ p3,
        const uint* __restrict__ wf1, const uint* __restrict__ wf2,
        const float* __restrict__ b1, const float* __restrict__ b2,
        const float* __restrict__ dinv, uint* __restrict__ z, int zstride) {
    __shared__ float hls[4 * 16 * LROW];
    int tid = threadIdx.x;
    int wv = tid >> 6, l = tid & 63, g = l >> 4, c = l & 15;
    float* my = hls + wv * 16 * LROW;
    int row0 = blockIdx.x * 64 + wv * 16;
    int ra = row0 + c;
    int rc = min(ra, N_NODES - 1);

    // ---- stage 1: A-frags straight from global ----
    uint4 au0;
    {
        float4 xa = *(const float4*)(x + rc * 32 + g * 8);
        float4 xb = *(const float4*)(x + rc * 32 + g * 8 + 4);
        au0.x = pack_bf16(xa.x, xa.y);
        au0.y = pack_bf16(xa.z, xa.w);
        au0.z = pack_bf16(xb.x, xb.y);
        au0.w = pack_bf16(xb.z, xb.w);
    }
    uint4 au1 = *(const uint4*)(p1 + rc * 16 + g * 4);
    uint4 au2 = *(const uint4*)(p2 + rc * 16 + g * 4);
    uint4 au3 = *(const uint4*)(p3 + rc * 16 + g * 4);
    s8v a0 = to_s8(au0), a1 = to_s8(au1), a2 = to_s8(au2), a3 = to_s8(au3);

    f4v acc[4];
#pragma unroll
    for (int nt = 0; nt < 4; nt++) {
        f4v ac = {0.f, 0.f, 0.f, 0.f};
        const s8v* wp = (const s8v*)(wf1 + (nt * 4) * 64 * 4 + l * 4);
        ac = __builtin_amdgcn_mfma_f32_16x16x32_bf16(a0, wp[0 * 64], ac, 0, 0, 0);
        ac = __builtin_amdgcn_mfma_f32_16x16x32_bf16(a1, wp[1 * 64], ac, 0, 0, 0);
        ac = __builtin_amdgcn_mfma_f32_16x16x32_bf16(a2, wp[2 * 64], ac, 0, 0, 0);
        ac = __builtin_amdgcn_mfma_f32_16x16x32_bf16(a3, wp[3 * 64], ac, 0, 0, 0);
        acc[nt] = ac;
    }

    // ---- epilogue 1: bias + relu -> padded LDS tile ----
#pragma unroll
    for (int nt = 0; nt < 4; nt++) {
        float bb = b1[nt * 16 + c];
#pragma unroll
        for (int reg = 0; reg < 4; reg++) {
            my[(4 * g + reg) * LROW + nt * 16 + c] = fmaxf(acc[nt][reg] + bb, 0.0f);
        }
    }
    __syncthreads();

    // ---- stage 2: re-fragment from LDS, second MFMA ----
    uint4 b2u[2];
#pragma unroll
    for (int ks = 0; ks < 2; ks++) {
        float4 h0 = *(const float4*)&my[c * LROW + ks * 32 + g * 8];
        float4 h1 = *(const float4*)&my[c * LROW + ks * 32 + g * 8 + 4];
        b2u[ks].x = pack_bf16(h0.x, h0.y);
        b2u[ks].y = pack_bf16(h0.z, h0.w);
        b2u[ks].z = pack_bf16(h1.x, h1.y);
        b2u[ks].w = pack_bf16(h1.z, h1.w);
    }
    s8v h0f = to_s8(b2u[0]), h1f = to_s8(b2u[1]);

    f4v acc2[4];
#pragma unroll
    for (int nt = 0; nt < 4; nt++) {
        f4v ac = {0.f, 0.f, 0.f, 0.f};
        const s8v* wp = (const s8v*)(wf2 + (nt * 2) * 64 * 4 + l * 4);
        ac = __builtin_amdgcn_mfma_f32_16x16x32_bf16(h0f, wp[0 * 64], ac, 0, 0, 0);
        ac = __builtin_amdgcn_mfma_f32_16x16x32_bf16(h1f, wp[1 * 64], ac, 0, 0, 0);
        acc2[nt] = ac;
    }

    // ---- epilogue 2: bias (k=0), dinv prescale (k=3), pack pairs via shfl, store bf16 z ----
#pragma unroll
    for (int nt = 0; nt < 4; nt++) {
        float bb = (nt == 0 && c < NCLS) ? b2[c] : 0.0f;
        uint* zk = z + (size_t)nt * zstride;
#pragma unroll
        for (int reg = 0; reg < 4; reg++) {
            int rr = row0 + 4 * g + reg;
            float v = acc2[nt][reg] + bb;
            if (nt == 3) v *= dinv[min(rr, N_NODES - 1)];
            float vn = __shfl_xor(v, 1);  // col c^1's value
            if (rr < N_NODES && (c & 1) == 0) {
                zk[rr * 8 + (c >> 1)] = pack_bf16(v, vn);
            }
        }
    }
}

// ---------------- launcher ----------------

extern "C" void kernel_launch(void* const* d_in, const int* in_sizes, int n_in,
                              void* d_out, int out_size, void* d_ws, size_t ws_size,
                              hipStream_t stream) {
    const float* x  = (const float*)d_in[0];
    const int*   ei = (const int*)d_in[1];
    const float* W1 = (const float*)d_in[2];
    const float* b1 = (const float*)d_in[3];
    const float* W2 = (const float*)d_in[4];
    const float* b2 = (const float*)d_in[5];
    float* out = (float*)d_out;

    const int* row = ei;
    const int* col = ei + N_EDGES;

    float* w = (float*)d_ws;
    size_t o = 0;
    auto alloc = [&](size_t nel) { float* p = w + o; o += (nel + 63) & ~(size_t)63; return p; };

    int*   rowptr = (int*)alloc(N_NODES + 1);
    int*   bsum   = (int*)alloc(512);
    float* dinv   = alloc(N_NODES);
    uint*  wf1    = (uint*)alloc(4096);
    uint*  wf2    = (uint*)alloc(2048);
    int*   eidx   = (int*)alloc(N_EDGES + 16);
    float* bufA   = alloc((size_t)N_NODES * 32);
    float* bufB   = alloc((size_t)N_NODES * 32);
    float* bufC   = alloc((size_t)N_NODES * 32);
    float* bufD   = alloc((size_t)N_NODES * 32);
    float* h      = alloc((size_t)N_NODES * HID);   // holds z0..z3 after dense

    // CSR-build temporaries alias later buffers (build completes first)
    int* blockhist = (int*)bufB;
    int* bhbase    = (int*)bufC;
    int* packed    = (int*)h;

    // layer-1 bf16 buffers (each 100k x 16 uints = 6.4 MB)
    uint* t0  = (uint*)bufA;
    uint* p1  = (uint*)bufB;
    uint* p1p = (uint*)bufC;
    uint* p2  = (uint*)bufD;
    uint* p2p = (uint*)bufA;   // t0 dead after hop1
    uint* p3  = (uint*)bufC;   // p1p dead after hop2
    // layer-2 bf16 z buffers (each 100k x 8 uints = 3.2 MB) live in h region
    const int ZS = N_NODES * 8;
    uint* z0  = (uint*)h;
    uint* z1  = (uint*)h + ZS;
    uint* z2  = (uint*)h + 2 * (size_t)ZS;
    uint* z3p = (uint*)h + 3 * (size_t)ZS;   // pre-scaled by dinv in dense_fused
    uint* tAp = (uint*)bufC;                 // bufC free after dense_fused
    uint* tBp = (uint*)bufC + ZS;

    const int TB = 256;
    const int gW = (N_NODES * 64) / TB;        // 25000: 1 node/wave kernels
    const int gW2 = ((N_NODES + 1) / 2 * 64 + TB - 1) / TB;  // 12500: 2 nodes/wave

    // --- CSR build ---
    bucket_hist<<<NCB, TB, 0, stream>>>(col, blockhist);
    scanA_kernel<<<NB_BH, TB, 0, stream>>>(blockhist, bhbase, bsum, BH_N);
    scanB_kernel<<<1, 512, 0, stream>>>(bsum, NB_BH);
    scanC_add<<<NB_BH, TB, 0, stream>>>(bhbase, bsum, BH_N);
    bucket_scatter<<<NCB, TB, 0, stream>>>(row, col, bhbase, packed);
    bucket_sort<<<NBUCKET, TB, 0, stream>>>(bhbase, packed, rowptr, eidx, dinv);

    // --- weight pre-pack (tiny) ---
    wfprep_kernel<<<24, TB, 0, stream>>>(W1, W2, wf1, wf2);

    // --- layer 1 (bf16 propagation) ---
    prescale_kernel<<<(N_NODES * 16 + TB - 1) / TB, TB, 0, stream>>>(x, dinv, t0);
    gather32_kernel<1><<<gW, TB, 0, stream>>>(rowptr, eidx, dinv, t0,  p1, p1p);
    gather32_kernel<1><<<gW, TB, 0, stream>>>(rowptr, eidx, dinv, p1p, p2, p2p);
    gather32_kernel<0><<<gW, TB, 0, stream>>>(rowptr, eidx, dinv, p2p, p3, nullptr);

    // --- fused dense: both layers' GEMMs on the matrix pipe ---
    int gF = (N_NODES + 63) / 64;  // 1563
    dense_fused<<<gF, TB, 0, stream>>>(x, p1, p2, p3, wf1, wf2, b1, b2, dinv, z0, ZS);

    // --- layer-2 Horner at width 16 (bf16) ---
    gather16_kernel<0><<<gW2, TB, 0, stream>>>(rowptr, eidx, dinv, z3p, z2, tAp);
    gather16_kernel<0><<<gW2, TB, 0, stream>>>(rowptr, eidx, dinv, tAp, z1, tBp);
    gather16_kernel<1><<<gW2, TB, 0, stream>>>(rowptr, eidx, dinv, tBp, z0, out);
}